// Round 3
// baseline (1029.427 us; speedup 1.0000x reference)
//
#include <hip/hip_runtime.h>

// RNN scan: B=2048, T=512, V=64, H=256, K=H+V=320.
// R3: 512 persistent blocks x 256 threads (4 waves), 4 batch rows per block ->
// 2 independent blocks per CU (2 waves/SIMD). Independent barriers anti-align,
// so the two latency chains interleave on the SIMDs (the R2 bottleneck was
// 1 wave/SIMD on half the CUs: every cycle of the ~2860cy/step chain exposed).
// M=16 MFMA tile carries only 4 live rows (75% waste, free while latency-bound).
// State rows 4-15 stay zero forever: zero-init both buffers, state writes
// predicated to q==0. Token lanes loc>=4 load duplicate rows (loc&3) -> C rows
// 4-15 are finite garbage, never read. Theta in VGPR B-frags; lgkm-only
// barriers keep token prefetch in flight across the step boundary.

#define TT 512
#define VV 64
#define HH 256
#define STRD 264   // ushorts per state row: 256 + 8 pad (33 x 16B -> conflict-free b128)

typedef short bf16x8 __attribute__((ext_vector_type(8)));
typedef float f32x4  __attribute__((ext_vector_type(4)));

__device__ __forceinline__ unsigned short f2bf(float f) {
    unsigned int u = __float_as_uint(f);
    return (unsigned short)((u + 0x8000u) >> 16);   // round-to-nearest
}

__device__ __forceinline__ float bf2f(unsigned short u) {
    return __uint_as_float(((unsigned int)u) << 16);
}

__device__ __forceinline__ bf16x8 pack8(float4 a, float4 b) {
    bf16x8 v;
    v[0] = (short)f2bf(a.x); v[1] = (short)f2bf(a.y);
    v[2] = (short)f2bf(a.z); v[3] = (short)f2bf(a.w);
    v[4] = (short)f2bf(b.x); v[5] = (short)f2bf(b.y);
    v[6] = (short)f2bf(b.z); v[7] = (short)f2bf(b.w);
    return v;
}

// x += dpp_perm(x); CTRL compile-time. VALU pipe (keeps LDS pipe free).
template <int CTRL>
__device__ __forceinline__ float dppadd(float x) {
    int y = __builtin_amdgcn_update_dpp(0, __float_as_int(x), CTRL, 0xF, 0xF, false);
    return x + __int_as_float(y);
}

// quad_perm broadcast: lanes 4a..4a+3 <- lane 4a + r (CTRL = rrrr pattern)
template <int CTRL>
__device__ __forceinline__ float dppbcast(float x) {
    int y = __builtin_amdgcn_update_dpp(0, __float_as_int(x), CTRL, 0xF, 0xF, true);
    return __int_as_float(y);
}

// s_barrier with LDS-only drain: do NOT drain vmcnt (keeps token prefetch in
// flight across the barrier). LDS visibility needs lgkmcnt(0) only.
__device__ __forceinline__ void barrier_lgkm() {
    asm volatile("s_waitcnt lgkmcnt(0)\n\ts_barrier" ::: "memory");
}

extern "C" __global__ void __launch_bounds__(256, 2)
rnn_scan_kernel(const float* __restrict__ seq,        // [2048][512][64]
                const float* __restrict__ theta,      // [256][320]
                const float* __restrict__ theta_dot,  // [256]
                float* __restrict__ out)              // [2048]
{
    __shared__ unsigned short stbuf[2][16][STRD];        // state, bf16, double-buffered
    __shared__ __align__(16) float2 partials[64];        // [row 0..15][wave 0..3] (sum, sumsq)

    const int tid = threadIdx.x;
    const int w   = tid >> 6;        // wave 0..3  -> N columns [64w, 64w+64)
    const int l   = tid & 63;        // lane
    const int q   = l >> 4;          // quad-row group 0..3
    const int loc = l & 15;
    const int r0  = blockIdx.x << 2; // first batch row of this block (4 rows)

    // ---- Theta -> resident B-fragments: bfrag[ks][s] covers K [32ks,32ks+32) x N [64w+16s, +16)
    bf16x8 bfrag[10][4];
#pragma unroll
    for (int s = 0; s < 4; ++s) {
        const float* trow = theta + (size_t)(w * 64 + s * 16 + loc) * 320;
#pragma unroll
        for (int ks = 0; ks < 10; ++ks) {
            float4 f0 = *(const float4*)(trow + ks * 32 + q * 8);
            float4 f1 = *(const float4*)(trow + ks * 32 + q * 8 + 4);
            bfrag[ks][s] = pack8(f0, f1);
        }
    }

    // ---- zero BOTH state buffers (rows 4-15 must stay zero forever) ----
    {
        const int m = tid >> 4, c = (tid & 15) * 16;
        uint4 z = make_uint4(0u, 0u, 0u, 0u);
        *(uint4*)(&stbuf[0][m][c])     = z;
        *(uint4*)(&stbuf[0][m][c + 8]) = z;
        *(uint4*)(&stbuf[1][m][c])     = z;
        *(uint4*)(&stbuf[1][m][c + 8]) = z;
    }

    // ---- prefetch token t=0 in A-frag layout: lane = row (loc&3), features q*8.. ----
    // lanes loc>=4 duplicate rows 0..3 (keeps loads uniform; C rows 4-15 discarded)
    const float* srow = seq + (size_t)(r0 + (loc & 3)) * (TT * VV);
    float4 tk0 = *(const float4*)(srow + q * 8);
    float4 tk1 = *(const float4*)(srow + q * 8 + 4);
    float4 tk2 = *(const float4*)(srow + 32 + q * 8);
    float4 tk3 = *(const float4*)(srow + 32 + q * 8 + 4);

    __syncthreads();

#pragma unroll 1
    for (int t = 0; t < TT; ++t) {
        unsigned short* stc = &stbuf[t & 1][0][0];
        unsigned short* stn = &stbuf[(t + 1) & 1][0][0];

        // token A-frags for this step (K blocks 8,9 = features 0..31 / 32..63)
        bf16x8 a8 = pack8(tk0, tk1);
        bf16x8 a9 = pack8(tk2, tk3);

        // prefetch next step's token; raw barriers keep it in flight until the
        // pack8 at the top of the next iteration (full-step latency cover)
        if (t + 1 < TT) {
            const float* p = srow + (size_t)(t + 1) * VV;
            tk0 = *(const float4*)(p + q * 8);
            tk1 = *(const float4*)(p + q * 8 + 4);
            tk2 = *(const float4*)(p + 32 + q * 8);
            tk3 = *(const float4*)(p + 32 + q * 8 + 4);
        }

        // ---- GEMM phase: z[rows 0..3 x 64w..] = [state|token] . theta^T ----
        f32x4 acc[4];
#pragma unroll
        for (int s = 0; s < 4; ++s) { acc[s][0] = 0.f; acc[s][1] = 0.f; acc[s][2] = 0.f; acc[s][3] = 0.f; }

        const unsigned short* arow = stc + loc * STRD;   // A-frag: lane = state row loc
#pragma unroll
        for (int ks = 0; ks < 8; ++ks) {
            bf16x8 av = *(const bf16x8*)(arow + ks * 32 + q * 8);  // ds_read_b128
#pragma unroll
            for (int s = 0; s < 4; ++s)
                acc[s] = __builtin_amdgcn_mfma_f32_16x16x32_bf16(av, bfrag[ks][s], acc[s], 0, 0, 0);
        }
#pragma unroll
        for (int s = 0; s < 4; ++s)
            acc[s] = __builtin_amdgcn_mfma_f32_16x16x32_bf16(a8, bfrag[8][s], acc[s], 0, 0, 0);
#pragma unroll
        for (int s = 0; s < 4; ++s)
            acc[s] = __builtin_amdgcn_mfma_f32_16x16x32_bf16(a9, bfrag[9][s], acc[s], 0, 0, 0);

        // ---- per-row partial stats over this wave's 64 columns ----
        // C layout: acc[s][r] is row q*4+r, col w*64 + s*16 + loc (rows >3 = garbage, contained)
        float sum[4], ssq[4];
#pragma unroll
        for (int r = 0; r < 4; ++r) {
            sum[r] = acc[0][r] + acc[1][r] + acc[2][r] + acc[3][r];
            ssq[r] = acc[0][r] * acc[0][r] + acc[1][r] * acc[1][r]
                   + acc[2][r] * acc[2][r] + acc[3][r] * acc[3][r];
        }
        // reduce across the 16 lanes of each quad-row group (DPP, VALU pipe)
#pragma unroll
        for (int r = 0; r < 4; ++r) {
            sum[r] = dppadd<0xB1>(sum[r]);  ssq[r] = dppadd<0xB1>(ssq[r]);   // quad_perm 1,0,3,2
            sum[r] = dppadd<0x4E>(sum[r]);  ssq[r] = dppadd<0x4E>(ssq[r]);   // quad_perm 2,3,0,1
            sum[r] = dppadd<0x124>(sum[r]); ssq[r] = dppadd<0x124>(ssq[r]);  // row_ror:4
            sum[r] = dppadd<0x128>(sum[r]); ssq[r] = dppadd<0x128>(ssq[r]);  // row_ror:8
        }
        if (loc < 4)
            partials[((q * 4 + loc) << 2) | w] = make_float2(sum[loc], ssq[loc]);

        barrier_lgkm();

        // ---- finalize stats: lane handles row q*4+(loc&3); only rows 0..3 live ----
        const int myrow = (q << 2) | (loc & 3);
        float4 pA = *(const float4*)(&partials[myrow << 2]);       // waves 0,1 (b128 broadcast)
        float4 pB = *(const float4*)(&partials[(myrow << 2) | 2]); // waves 2,3
        float sumT = (pA.x + pA.z) + (pB.x + pB.z);
        float ssqT = (pA.y + pA.w) + (pB.y + pB.w);
        float mean = sumT * (1.0f / 256.0f);
        float var  = (ssqT - sumT * mean) * (1.0f / 255.0f);   // ddof=1 (Bessel)
        float rstd = rsqrtf(var);
        float nb   = -mean * rstd;                              // v = fma(z, rstd, nb)

        // broadcast (rstd, nb) for rows q*4+r to all lanes of each nibble (VALU DPP)
        float rs[4], nbv[4];
        rs[0] = dppbcast<0x00>(rstd); nbv[0] = dppbcast<0x00>(nb);
        rs[1] = dppbcast<0x55>(rstd); nbv[1] = dppbcast<0x55>(nb);
        rs[2] = dppbcast<0xAA>(rstd); nbv[2] = dppbcast<0xAA>(nb);
        rs[3] = dppbcast<0xFF>(rstd); nbv[3] = dppbcast<0xFF>(nb);

        // ---- normalize, relu, write next-state bf16 (rows 0..3 only: q==0) ----
        if (q == 0) {
#pragma unroll
            for (int s = 0; s < 4; ++s) {
#pragma unroll
                for (int r = 0; r < 4; ++r) {
                    float v = fmaf(acc[s][r], rs[r], nbv[r]);
                    v = fmaxf(v, 0.0f);
                    stn[r * STRD + (w * 64 + s * 16 + loc)] = f2bf(v);
                }
            }
        }
        barrier_lgkm();
    }

    // ---- readout: logits = state . theta_dot ; out = sigmoid(logits) ----
    // final state is in buffer (T & 1) ^ 1 == 0; only rows 0..3 live
    {
        const int m = tid >> 4, c0 = (tid & 15) << 4;
        const unsigned short* sr = &stbuf[0][m][c0];
        float dot = 0.0f;
#pragma unroll
        for (int j = 0; j < 16; ++j)
            dot += bf2f(sr[j]) * theta_dot[c0 + j];
        dot += __shfl_xor(dot, 1, 64);
        dot += __shfl_xor(dot, 2, 64);
        dot += __shfl_xor(dot, 4, 64);
        dot += __shfl_xor(dot, 8, 64);
        if ((tid & 15) == 0 && m < 4)
            out[r0 + m] = 1.0f / (1.0f + expf(-dot));
    }
}

extern "C" void kernel_launch(void* const* d_in, const int* in_sizes, int n_in,
                              void* d_out, int out_size, void* d_ws, size_t ws_size,
                              hipStream_t stream) {
    const float* seq   = (const float*)d_in[0];  // [2048*512*64]
    const float* theta = (const float*)d_in[1];  // [256*320]
    // d_in[2] = bias[1]: constant shift cancels exactly in LayerNorm -> unused
    const float* tdot  = (const float*)d_in[3];  // [256]
    float* out = (float*)d_out;

    rnn_scan_kernel<<<dim3(512), dim3(256), 0, stream>>>(seq, theta, tdot, out);
}

// Round 4
// 893.067 us; speedup vs baseline: 1.1527x; 1.1527x over previous
//
#include <hip/hip_runtime.h>

// RNN scan: B=2048, T=512, V=64, H=256, K=H+V=320.
// R4: 128 persistent blocks x 512 threads (8 waves), 16 batch rows per block.
// Each wave owns N=32 columns -> bfrag[10][2] = 80 VGPRs (R3's 160-VGPR bfrag
// spilled to scratch under launch_bounds(256,2): VGPR 128 + 42MB scratch writes).
// 8 waves/CU = 2 waves/SIMD: two independent streams hide MFMA/LDS/DPP latency.
// Parallelism ceiling is structural: LN couples H=256 -> B/16 = 128 blocks;
// extra blocks only compute tile padding (R3 measured this: 4x blocks, slower).
// Theta in VGPR B-frags; state double-buffered bf16 in LDS; lgkm-only barriers
// keep token prefetch in flight; LN via DPP + padded-LDS cross-wave combine.

#define TT 512
#define VV 64
#define HH 256
#define STRD 264   // ushorts per state row: 256 + 8 pad (33 x 16B); b128-aligned

typedef short bf16x8 __attribute__((ext_vector_type(8)));
typedef float f32x4  __attribute__((ext_vector_type(4)));

__device__ __forceinline__ unsigned short f2bf(float f) {
    unsigned int u = __float_as_uint(f);
    return (unsigned short)((u + 0x8000u) >> 16);   // round-to-nearest
}

__device__ __forceinline__ float bf2f(unsigned short u) {
    return __uint_as_float(((unsigned int)u) << 16);
}

__device__ __forceinline__ bf16x8 pack8(float4 a, float4 b) {
    bf16x8 v;
    v[0] = (short)f2bf(a.x); v[1] = (short)f2bf(a.y);
    v[2] = (short)f2bf(a.z); v[3] = (short)f2bf(a.w);
    v[4] = (short)f2bf(b.x); v[5] = (short)f2bf(b.y);
    v[6] = (short)f2bf(b.z); v[7] = (short)f2bf(b.w);
    return v;
}

// x += dpp_perm(x); CTRL compile-time. VALU pipe (keeps LDS pipe free).
template <int CTRL>
__device__ __forceinline__ float dppadd(float x) {
    int y = __builtin_amdgcn_update_dpp(0, __float_as_int(x), CTRL, 0xF, 0xF, false);
    return x + __int_as_float(y);
}

// quad_perm broadcast: lanes 4a..4a+3 <- lane 4a+r (CTRL = rrrr pattern)
template <int CTRL>
__device__ __forceinline__ float dppbcast(float x) {
    int y = __builtin_amdgcn_update_dpp(0, __float_as_int(x), CTRL, 0xF, 0xF, true);
    return __int_as_float(y);
}

// s_barrier with LDS-only drain: do NOT drain vmcnt (keeps token prefetch in
// flight across the barrier). LDS visibility needs lgkmcnt(0) only.
__device__ __forceinline__ void barrier_lgkm() {
    asm volatile("s_waitcnt lgkmcnt(0)\n\ts_barrier" ::: "memory");
}

extern "C" __global__ void __launch_bounds__(512, 2)
rnn_scan_kernel(const float* __restrict__ seq,        // [2048][512][64]
                const float* __restrict__ theta,      // [256][320]
                const float* __restrict__ theta_dot,  // [256]
                float* __restrict__ out)              // [2048]
{
    __shared__ unsigned short stbuf[2][16][STRD];        // state, bf16, double-buffered
    __shared__ __align__(16) float2 partials[16][10];    // [row][wave 0..7 + 2 pad]
                                                         // 80B row stride = 20 banks ->
                                                         // finalize b128 reads conflict-free

    const int tid = threadIdx.x;
    const int w   = tid >> 6;        // wave 0..7  -> N columns [32w, 32w+32)
    const int l   = tid & 63;        // lane
    const int q   = l >> 4;          // quad-row group 0..3
    const int loc = l & 15;
    const int r0  = blockIdx.x << 4; // first batch row of this block (16 rows)

    // ---- Theta -> resident B-fragments: bfrag[ks][s] covers K [32ks,32ks+32) x N [32w+16s, +16)
    // 80 VGPRs/wave (vs R2/R3's 160): the no-spill budget for 2 waves/SIMD.
    bf16x8 bfrag[10][2];
#pragma unroll
    for (int s = 0; s < 2; ++s) {
        const float* trow = theta + (size_t)(w * 32 + s * 16 + loc) * 320;
#pragma unroll
        for (int ks = 0; ks < 10; ++ks) {
            float4 f0 = *(const float4*)(trow + ks * 32 + q * 8);
            float4 f1 = *(const float4*)(trow + ks * 32 + q * 8 + 4);
            bfrag[ks][s] = pack8(f0, f1);
        }
    }

    // ---- zero initial state (buffer 0): 512 threads cover 16 x 256 ushorts ----
    {
        const int m = tid >> 5, c = (tid & 31) * 8;   // 8 ushorts = 16B per thread
        uint4 z = make_uint4(0u, 0u, 0u, 0u);
        *(uint4*)(&stbuf[0][m][c]) = z;
    }

    // ---- prefetch token t=0 in A-frag layout: lane = row loc, features q*8.. ----
    const float* srow = seq + (size_t)(r0 + loc) * (TT * VV);
    float4 tk0 = *(const float4*)(srow + q * 8);
    float4 tk1 = *(const float4*)(srow + q * 8 + 4);
    float4 tk2 = *(const float4*)(srow + 32 + q * 8);
    float4 tk3 = *(const float4*)(srow + 32 + q * 8 + 4);

    __syncthreads();

#pragma unroll 1
    for (int t = 0; t < TT; ++t) {
        unsigned short* stc = &stbuf[t & 1][0][0];
        unsigned short* stn = &stbuf[(t + 1) & 1][0][0];

        // token A-frags for this step (K blocks 8,9 = features 0..31 / 32..63)
        bf16x8 a8 = pack8(tk0, tk1);
        bf16x8 a9 = pack8(tk2, tk3);

        // prefetch next step's token; raw barriers keep it in flight until the
        // pack8 at the top of the next iteration (full-step latency cover)
        if (t + 1 < TT) {
            const float* p = srow + (size_t)(t + 1) * VV;
            tk0 = *(const float4*)(p + q * 8);
            tk1 = *(const float4*)(p + q * 8 + 4);
            tk2 = *(const float4*)(p + 32 + q * 8);
            tk3 = *(const float4*)(p + 32 + q * 8 + 4);
        }

        // ---- GEMM phase: z[16 x N-slice] = [state|token] . theta^T ----
        f32x4 acc[2];
        acc[0][0] = 0.f; acc[0][1] = 0.f; acc[0][2] = 0.f; acc[0][3] = 0.f;
        acc[1][0] = 0.f; acc[1][1] = 0.f; acc[1][2] = 0.f; acc[1][3] = 0.f;

        const unsigned short* arow = stc + loc * STRD;   // A-frag: lane = state row loc
#pragma unroll
        for (int ks = 0; ks < 8; ++ks) {
            bf16x8 av = *(const bf16x8*)(arow + ks * 32 + q * 8);  // ds_read_b128
            acc[0] = __builtin_amdgcn_mfma_f32_16x16x32_bf16(av, bfrag[ks][0], acc[0], 0, 0, 0);
            acc[1] = __builtin_amdgcn_mfma_f32_16x16x32_bf16(av, bfrag[ks][1], acc[1], 0, 0, 0);
        }
        acc[0] = __builtin_amdgcn_mfma_f32_16x16x32_bf16(a8, bfrag[8][0], acc[0], 0, 0, 0);
        acc[1] = __builtin_amdgcn_mfma_f32_16x16x32_bf16(a8, bfrag[8][1], acc[1], 0, 0, 0);
        acc[0] = __builtin_amdgcn_mfma_f32_16x16x32_bf16(a9, bfrag[9][0], acc[0], 0, 0, 0);
        acc[1] = __builtin_amdgcn_mfma_f32_16x16x32_bf16(a9, bfrag[9][1], acc[1], 0, 0, 0);

        // ---- per-row partial stats over this wave's 32 columns ----
        // C layout: acc[s][r] is row q*4+r, col 32w + s*16 + loc
        float sum[4], ssq[4];
#pragma unroll
        for (int r = 0; r < 4; ++r) {
            sum[r] = acc[0][r] + acc[1][r];
            ssq[r] = acc[0][r] * acc[0][r] + acc[1][r] * acc[1][r];
        }
        // reduce across the 16 lanes of each quad-row group (DPP, VALU pipe)
#pragma unroll
        for (int r = 0; r < 4; ++r) {
            sum[r] = dppadd<0xB1>(sum[r]);  ssq[r] = dppadd<0xB1>(ssq[r]);   // quad_perm 1,0,3,2
            sum[r] = dppadd<0x4E>(sum[r]);  ssq[r] = dppadd<0x4E>(ssq[r]);   // quad_perm 2,3,0,1
            sum[r] = dppadd<0x124>(sum[r]); ssq[r] = dppadd<0x124>(ssq[r]);  // row_ror:4
            sum[r] = dppadd<0x128>(sum[r]); ssq[r] = dppadd<0x128>(ssq[r]);  // row_ror:8
        }
        if (loc < 4)
            partials[q * 4 + loc][w] = make_float2(sum[loc], ssq[loc]);

        barrier_lgkm();

        // ---- finalize stats: lane handles row q*4+(loc&3) (4 replicas/row) ----
        // partials[row][0..7] = 4 x b128; 20-bank row stride -> worst 2-way (free)
        const int myrow = (q << 2) | (loc & 3);
        float4 p0 = *(const float4*)(&partials[myrow][0]);   // waves 0,1
        float4 p1 = *(const float4*)(&partials[myrow][2]);   // waves 2,3
        float4 p2 = *(const float4*)(&partials[myrow][4]);   // waves 4,5
        float4 p3 = *(const float4*)(&partials[myrow][6]);   // waves 6,7
        float sumT = ((p0.x + p0.z) + (p1.x + p1.z)) + ((p2.x + p2.z) + (p3.x + p3.z));
        float ssqT = ((p0.y + p0.w) + (p1.y + p1.w)) + ((p2.y + p2.w) + (p3.y + p3.w));
        float mean = sumT * (1.0f / 256.0f);
        float var  = (ssqT - sumT * mean) * (1.0f / 255.0f);   // ddof=1 (Bessel)
        float rstd = rsqrtf(var);
        float nb   = -mean * rstd;                              // v = fma(z, rstd, nb)

        // broadcast (rstd, nb) for rows q*4+r to all lanes of each nibble (VALU DPP)
        float rs[4], nbv[4];
        rs[0] = dppbcast<0x00>(rstd); nbv[0] = dppbcast<0x00>(nb);
        rs[1] = dppbcast<0x55>(rstd); nbv[1] = dppbcast<0x55>(nb);
        rs[2] = dppbcast<0xAA>(rstd); nbv[2] = dppbcast<0xAA>(nb);
        rs[3] = dppbcast<0xFF>(rstd); nbv[3] = dppbcast<0xFF>(nb);

        // ---- normalize, relu, write next-state bf16 ----
#pragma unroll
        for (int s = 0; s < 2; ++s) {
#pragma unroll
            for (int r = 0; r < 4; ++r) {
                float v = fmaf(acc[s][r], rs[r], nbv[r]);
                v = fmaxf(v, 0.0f);
                stn[(q * 4 + r) * STRD + (w * 32 + s * 16 + loc)] = f2bf(v);
            }
        }
        barrier_lgkm();
    }

    // ---- readout: logits = state . theta_dot ; out = sigmoid(logits) ----
    // final state is in buffer (T & 1) ^ 1 == 0
    if (tid < 256) {
        const int m = tid >> 4, c0 = (tid & 15) << 4;
        const unsigned short* sr = &stbuf[0][m][c0];
        float dot = 0.0f;
#pragma unroll
        for (int j = 0; j < 16; ++j)
            dot += bf2f(sr[j]) * theta_dot[c0 + j];
        dot += __shfl_xor(dot, 1, 64);
        dot += __shfl_xor(dot, 2, 64);
        dot += __shfl_xor(dot, 4, 64);
        dot += __shfl_xor(dot, 8, 64);
        if ((tid & 15) == 0)
            out[r0 + m] = 1.0f / (1.0f + expf(-dot));
    }
}

extern "C" void kernel_launch(void* const* d_in, const int* in_sizes, int n_in,
                              void* d_out, int out_size, void* d_ws, size_t ws_size,
                              hipStream_t stream) {
    const float* seq   = (const float*)d_in[0];  // [2048*512*64]
    const float* theta = (const float*)d_in[1];  // [256*320]
    // d_in[2] = bias[1]: constant shift cancels exactly in LayerNorm -> unused
    const float* tdot  = (const float*)d_in[3];  // [256]
    float* out = (float*)d_out;

    rnn_scan_kernel<<<dim3(128), dim3(512), 0, stream>>>(seq, theta, tdot, out);
}

// Round 5
// 874.497 us; speedup vs baseline: 1.1772x; 1.0212x over previous
//
#include <hip/hip_runtime.h>
#include <hip/hip_bf16.h>

// RNN scan: B=2048, T=512, V=64, H=256, K=H+V=320.
// R5: algebraic restructuring of the step to shrink the barrier-synchronized
// critical chain (R2-R4 showed waves can't hide it; the chain IS the time).
//  - Mean-free GEMM: W~ = W - colmean(W) computed once -> LN mean path gone
//    (bias cancels exactly in the centering).
//  - Deferred normalization: state stored as u = relu(acc)/d_prev (relu is
//    positively homogeneous; next GEMM is linear in state). The missing 1/d
//    folds into the NEXT step's per-row token scale D = d_t/d_{t-1}.
//    => ONE barrier per step; ssq finalize moves off the critical path.
//  - partials double-buffered (WAR across the single barrier).
// 128 blocks x 256 threads (4 waves, N=64/wave), Theta in VGPR B-frags
// (160 VGPR/wave; launch_bounds(256,1) - the no-spill config, cf. R3 spill).

#define TT 512
#define VV 64
#define STRD 264   // ushorts per state row: 256 + 8 pad

typedef short bf16x8 __attribute__((ext_vector_type(8)));
typedef float f32x4  __attribute__((ext_vector_type(4)));

__device__ __forceinline__ float bf2f(unsigned short u) {
    return __uint_as_float(((unsigned int)u) << 16);
}

__device__ __forceinline__ unsigned int pkbf(float a, float b) {
    __hip_bfloat162 h = __float22bfloat162_rn(make_float2(a, b));  // v_cvt_pk_bf16_f32
    unsigned int u; __builtin_memcpy(&u, &h, 4); return u;
}

__device__ __forceinline__ bf16x8 pack8s(float4 a, float4 b, float s) {
    union { bf16x8 v; unsigned int u[4]; } r;
    r.u[0] = pkbf(a.x * s, a.y * s);
    r.u[1] = pkbf(a.z * s, a.w * s);
    r.u[2] = pkbf(b.x * s, b.y * s);
    r.u[3] = pkbf(b.z * s, b.w * s);
    return r.v;
}

// x += dpp_perm(x); VALU pipe.
template <int CTRL>
__device__ __forceinline__ float dppadd(float x) {
    int y = __builtin_amdgcn_update_dpp(0, __float_as_int(x), CTRL, 0xF, 0xF, false);
    return x + __int_as_float(y);
}

// quad_perm broadcast rrrr: all 4 lanes of each quad get lane (4a+r)'s value
template <int CTRL>
__device__ __forceinline__ float dppbcast(float x) {
    int y = __builtin_amdgcn_update_dpp(0, __float_as_int(x), CTRL, 0xF, 0xF, true);
    return __int_as_float(y);
}

// Barrier with LDS-only drain: token prefetch (vmcnt) stays in flight.
__device__ __forceinline__ void barrier_lgkm() {
    asm volatile("s_waitcnt lgkmcnt(0)\n\ts_barrier" ::: "memory");
}

extern "C" __global__ void __launch_bounds__(256, 1)
rnn_scan_kernel(const float* __restrict__ seq,        // [2048][512][64]
                const float* __restrict__ theta,      // [256][320]
                const float* __restrict__ theta_dot,  // [256]
                float* __restrict__ out)              // [2048]
{
    __shared__ unsigned short stbuf[2][16][STRD];     // unnormalized relu-state, bf16
    __shared__ __align__(16) float partials[2][16][4];// ssq(acc) per [buf][row][wave]
    __shared__ float cmean[320];
    __shared__ float dfin[16];

    const int tid = threadIdx.x;
    const int w   = tid >> 6;        // wave 0..3 -> N columns [64w, 64w+64)
    const int l   = tid & 63;
    const int q   = l >> 4;          // quad-row group
    const int loc = l & 15;
    const int r0  = blockIdx.x << 4; // 16 batch rows per block

    // ---- one-time: column means of theta (for mean-free W~) ----
    for (int c = tid; c < 320; c += 256) {
        float s0 = 0.f, s1 = 0.f, s2 = 0.f, s3 = 0.f;
        for (int i = 0; i < 256; i += 4) {
            s0 += theta[(i + 0) * 320 + c];
            s1 += theta[(i + 1) * 320 + c];
            s2 += theta[(i + 2) * 320 + c];
            s3 += theta[(i + 3) * 320 + c];
        }
        cmean[c] = ((s0 + s1) + (s2 + s3)) * (1.0f / 256.0f);
    }
    __syncthreads();

    // ---- Theta~ -> resident B-fragments (centered): bfrag[ks][s] ----
    bf16x8 bfrag[10][4];
#pragma unroll
    for (int s = 0; s < 4; ++s) {
        const float* trow = theta + (size_t)(w * 64 + s * 16 + loc) * 320;
#pragma unroll
        for (int ks = 0; ks < 10; ++ks) {
            float4 f0 = *(const float4*)(trow + ks * 32 + q * 8);
            float4 f1 = *(const float4*)(trow + ks * 32 + q * 8 + 4);
            float4 c0 = *(const float4*)(&cmean[ks * 32 + q * 8]);
            float4 c1 = *(const float4*)(&cmean[ks * 32 + q * 8 + 4]);
            f0.x -= c0.x; f0.y -= c0.y; f0.z -= c0.z; f0.w -= c0.w;
            f1.x -= c1.x; f1.y -= c1.y; f1.z -= c1.z; f1.w -= c1.w;
            bfrag[ks][s] = pack8s(f0, f1, 1.0f);
        }
    }

    // ---- zero initial state (buffer 0) ----
    {
        const int m = tid >> 4, c = (tid & 15) * 16;
        uint4 z = make_uint4(0u, 0u, 0u, 0u);
        *(uint4*)(&stbuf[0][m][c])     = z;
        *(uint4*)(&stbuf[0][m][c + 8]) = z;
    }

    // ---- prefetch token t=0 in A-frag layout: lane = row loc ----
    const float* srow = seq + (size_t)(r0 + loc) * (TT * VV);
    float4 tk0 = *(const float4*)(srow + q * 8);
    float4 tk1 = *(const float4*)(srow + q * 8 + 4);
    float4 tk2 = *(const float4*)(srow + 32 + q * 8);
    float4 tk3 = *(const float4*)(srow + 32 + q * 8 + 4);

    barrier_lgkm();

    float dprev = 1.0f;   // d^_{t-2} for row loc (token-scale recursion)

#pragma unroll 1
    for (int t = 0; t < TT; ++t) {
        unsigned short* stc = &stbuf[t & 1][0][0];
        unsigned short* stn = &stbuf[(t + 1) & 1][0][0];

        // ---- finalize last step's stats (off the pre-barrier critical path) ----
        float Dtok = 1.0f, g = 1.0f;
        if (t) {
            // token-scale path: row = loc (A-frag row of this lane)
            float4 pa = *(const float4*)(&partials[(t + 1) & 1][loc][0]);
            float dh = sqrtf(((pa.x + pa.y) + (pa.z + pa.w)) * (1.0f / 255.0f));
            Dtok  = dh * __builtin_amdgcn_rcpf(dprev);
            dprev = dh;
            // write-scale path: row = q*4 + (l&3) (C-layout rows via quad_perm)
            const int wrow = (q << 2) | (l & 3);
            float4 pb = *(const float4*)(&partials[(t + 1) & 1][wrow][0]);
            float dw = sqrtf(((pb.x + pb.y) + (pb.z + pb.w)) * (1.0f / 255.0f));
            g = __builtin_amdgcn_rcpf(dw);
        }
        float gr0 = dppbcast<0x00>(g), gr1 = dppbcast<0x55>(g);
        float gr2 = dppbcast<0xAA>(g), gr3 = dppbcast<0xFF>(g);

        // token A-frags, scaled by Dtok (per-row: lane = row loc)
        bf16x8 a8 = pack8s(tk0, tk1, Dtok);
        bf16x8 a9 = pack8s(tk2, tk3, Dtok);

        // prefetch next token (in flight across the barrier: lgkm-only drain)
        if (t + 1 < TT) {
            const float* p = srow + (size_t)(t + 1) * VV;
            tk0 = *(const float4*)(p + q * 8);
            tk1 = *(const float4*)(p + q * 8 + 4);
            tk2 = *(const float4*)(p + 32 + q * 8);
            tk3 = *(const float4*)(p + 32 + q * 8 + 4);
        }

        // ---- GEMM: acc = W~_h . u_{t-1} + W~_x . (Dtok x_t)  (mean-free) ----
        f32x4 acc[4];
#pragma unroll
        for (int s = 0; s < 4; ++s) { acc[s][0] = 0.f; acc[s][1] = 0.f; acc[s][2] = 0.f; acc[s][3] = 0.f; }

        const unsigned short* arow = stc + loc * STRD;
#pragma unroll
        for (int ks = 0; ks < 8; ++ks) {
            bf16x8 av = *(const bf16x8*)(arow + ks * 32 + q * 8);  // ds_read_b128
#pragma unroll
            for (int s = 0; s < 4; ++s)
                acc[s] = __builtin_amdgcn_mfma_f32_16x16x32_bf16(av, bfrag[ks][s], acc[s], 0, 0, 0);
        }
#pragma unroll
        for (int s = 0; s < 4; ++s)
            acc[s] = __builtin_amdgcn_mfma_f32_16x16x32_bf16(a8, bfrag[8][s], acc[s], 0, 0, 0);
#pragma unroll
        for (int s = 0; s < 4; ++s)
            acc[s] = __builtin_amdgcn_mfma_f32_16x16x32_bf16(a9, bfrag[9][s], acc[s], 0, 0, 0);

        // ---- per-row ssq over this wave's 64 columns (single stat!) ----
        float ssq[4];
#pragma unroll
        for (int r = 0; r < 4; ++r) {
            ssq[r] = acc[0][r] * acc[0][r] + acc[1][r] * acc[1][r]
                   + acc[2][r] * acc[2][r] + acc[3][r] * acc[3][r];
        }
#pragma unroll
        for (int r = 0; r < 4; ++r) {
            ssq[r] = dppadd<0xB1>(ssq[r]);   // quad_perm 1,0,3,2
            ssq[r] = dppadd<0x4E>(ssq[r]);   // quad_perm 2,3,0,1
            ssq[r] = dppadd<0x124>(ssq[r]);  // row_ror:4
            ssq[r] = dppadd<0x128>(ssq[r]);  // row_ror:8
        }
        if (loc < 4)
            partials[t & 1][q * 4 + loc][w] = ssq[loc];

        // ---- write unnormalized state u = relu(acc) * g (bf16, packed cvt) ----
#pragma unroll
        for (int s = 0; s < 4; ++s) {
            const int col = w * 64 + s * 16 + loc;
            unsigned int u01 = pkbf(fmaxf(acc[s][0], 0.f) * gr0, fmaxf(acc[s][1], 0.f) * gr1);
            unsigned int u23 = pkbf(fmaxf(acc[s][2], 0.f) * gr2, fmaxf(acc[s][3], 0.f) * gr3);
            stn[(q * 4 + 0) * STRD + col] = (unsigned short)(u01 & 0xffffu);
            stn[(q * 4 + 1) * STRD + col] = (unsigned short)(u01 >> 16);
            stn[(q * 4 + 2) * STRD + col] = (unsigned short)(u23 & 0xffffu);
            stn[(q * 4 + 3) * STRD + col] = (unsigned short)(u23 >> 16);
        }

        barrier_lgkm();   // the ONE barrier per step
    }

    // ---- epilogue: final divisor D_511 = d^_511 / d^_510 per row ----
    {
        float4 pa = *(const float4*)(&partials[(TT - 1) & 1][loc][0]);
        float dh = sqrtf(((pa.x + pa.y) + (pa.z + pa.w)) * (1.0f / 255.0f));
        float Dfin = dh * __builtin_amdgcn_rcpf(dprev);
        if (w == 0 && q == 0) dfin[loc] = Dfin;
    }
    barrier_lgkm();

    // ---- readout: logits = (u_T . theta_dot) / Dfin ; out = sigmoid ----
    // final u is in stbuf[(TT) & 1 ^ ...] = stbuf[0] (t=511 wrote (t+1)&1 = 0)
    {
        const int m = tid >> 4, c0 = (tid & 15) << 4;
        const unsigned short* sr = &stbuf[0][m][c0];
        float dot = 0.0f;
#pragma unroll
        for (int j = 0; j < 16; ++j)
            dot += bf2f(sr[j]) * theta_dot[c0 + j];
        dot += __shfl_xor(dot, 1, 64);
        dot += __shfl_xor(dot, 2, 64);
        dot += __shfl_xor(dot, 4, 64);
        dot += __shfl_xor(dot, 8, 64);
        if ((tid & 15) == 0) {
            float logit = dot / dfin[m];
            out[r0 + m] = 1.0f / (1.0f + expf(-logit));
        }
    }
}

extern "C" void kernel_launch(void* const* d_in, const int* in_sizes, int n_in,
                              void* d_out, int out_size, void* d_ws, size_t ws_size,
                              hipStream_t stream) {
    const float* seq   = (const float*)d_in[0];  // [2048*512*64]
    const float* theta = (const float*)d_in[1];  // [256*320]
    // d_in[2] = bias[1]: cancels exactly in the mean-centering -> unused
    const float* tdot  = (const float*)d_in[3];  // [256]
    float* out = (float*)d_out;

    rnn_scan_kernel<<<dim3(128), dim3(256), 0, stream>>>(seq, theta, tdot, out);
}